// Round 1
// baseline (20.524 us; speedup 1.0000x reference)
//
#include <hip/hip_runtime.h>

constexpr int N_ = 16, L_ = 196, D_ = 1024, T_ = 32;

// Kernel 1: scores[n*L + l] = dot(img[n,l,:], w)
// grid (L, N), 256 threads; each thread one float4 (256*4 = 1024 = D)
__global__ __launch_bounds__(256) void scores_kernel(const float* __restrict__ img,
                                                     const float* __restrict__ w,
                                                     float* __restrict__ scores) {
    const int l = blockIdx.x, n = blockIdx.y;
    const int tid = threadIdx.x;
    const float4* imgrow = reinterpret_cast<const float4*>(img + (size_t)(n * L_ + l) * D_);
    const float4* w4 = reinterpret_cast<const float4*>(w);
    float4 a = imgrow[tid];
    float4 b = w4[tid];
    float s = a.x * b.x + a.y * b.y + a.z * b.z + a.w * b.w;
    // wave (64-lane) reduction
    #pragma unroll
    for (int off = 32; off > 0; off >>= 1) s += __shfl_down(s, off);
    __shared__ float red[4];
    const int wave = tid >> 6, lane = tid & 63;
    if (lane == 0) red[wave] = s;
    __syncthreads();
    if (tid == 0) scores[n * L_ + l] = red[0] + red[1] + red[2] + red[3];
}

// Kernel 2: per-block softmax over L (redundant per d-chunk, cheap: 196 vals),
// then ctx[d] = sum_l p[l]*img[n,l,d], then out[n,t,d] = qes[n,t,d] + ctx[d].
// grid (D/256, N), 256 threads.
__global__ __launch_bounds__(256) void ctx_kernel(const float* __restrict__ img,
                                                  const float* __restrict__ qes,
                                                  const float* __restrict__ scores,
                                                  float* __restrict__ out) {
    const int n = blockIdx.y;
    const int tid = threadIdx.x;
    __shared__ float p[L_];
    __shared__ float red[8];

    float v = (tid < L_) ? scores[n * L_ + tid] : -INFINITY;
    // block max
    float m = v;
    #pragma unroll
    for (int off = 32; off > 0; off >>= 1) m = fmaxf(m, __shfl_down(m, off));
    const int wave = tid >> 6, lane = tid & 63;
    if (lane == 0) red[wave] = m;
    __syncthreads();
    const float bm = fmaxf(fmaxf(red[0], red[1]), fmaxf(red[2], red[3]));
    // block sum of exp
    float e = (tid < L_) ? __expf(v - bm) : 0.0f;
    float s = e;
    #pragma unroll
    for (int off = 32; off > 0; off >>= 1) s += __shfl_down(s, off);
    if (lane == 0) red[4 + wave] = s;
    __syncthreads();
    const float bs = red[4] + red[5] + red[6] + red[7];
    if (tid < L_) p[tid] = e / bs;
    __syncthreads();

    const int d = blockIdx.x * 256 + tid;
    const float* imgn = img + (size_t)n * L_ * D_;
    float acc = 0.0f;
    #pragma unroll 4
    for (int l = 0; l < L_; ++l)
        acc = fmaf(p[l], imgn[(size_t)l * D_ + d], acc);

    const float* qn = qes + (size_t)n * T_ * D_;
    float* on = out + (size_t)n * T_ * D_;
    #pragma unroll 8
    for (int t = 0; t < T_; ++t)
        on[t * D_ + d] = qn[t * D_ + d] + acc;
}

extern "C" void kernel_launch(void* const* d_in, const int* in_sizes, int n_in,
                              void* d_out, int out_size, void* d_ws, size_t ws_size,
                              hipStream_t stream) {
    const float* img = (const float*)d_in[0];   // [N, L, D]
    const float* qes = (const float*)d_in[1];   // [N, T, D]
    const float* w   = (const float*)d_in[2];   // [D]
    float* out = (float*)d_out;                 // [N, T, D]
    float* scores = (float*)d_ws;               // N*L floats = 12.5 KB

    scores_kernel<<<dim3(L_, N_), 256, 0, stream>>>(img, w, scores);
    ctx_kernel<<<dim3(D_ / 256, N_), 256, 0, stream>>>(img, qes, scores, out);
}